// Round 11
// baseline (817.629 us; speedup 1.0000x reference)
//
#include <hip/hip_runtime.h>
#include <stdint.h>

// GCN, DIM=1. Build: count_chunks -> chunk_scan -> place1 (bins = 16K-dst
// bucket x 4 src-blocks = 248; rec = dstloc14<<18 | srcloc18) -> wplace
// (per-bin 1024-src window sort, NW=256: 16KB active write lines/block, no
// writeback thrash). Layers: wave_agg -- each wave stages its 4KB window
// into a PRIVATE LDS slab (coalesced float4, reg-prefetch next window) and
// processes ~250 edges with pure LDS ops; no block barriers in the loop.
// Cuts VMEM line-requests ~17M -> ~5M per pass without barrier serialization.

static constexpr int NGRAPHS  = 256;
static constexpr int TB       = 256;
static constexpr int TB_P     = 512;    // place block
static constexpr int NCHUNK   = 256;    // edge chunks (count & place)
static constexpr int DSTB_LOG = 14;
static constexpr int DSTB     = 1 << DSTB_LOG;   // 16384 dst nodes per bucket
static constexpr int NSB_LOG  = 2;               // 4 src blocks
static constexpr int SRCB_LOG = 18;              // 256K srcs per block
static constexpr uint32_t SRCMASK = (1u << SRCB_LOG) - 1;
static constexpr int MAXB     = 256;             // max bins
static constexpr int WLOG     = 10;              // 1024-src windows (4KB)
static constexpr int NWIN     = 1 << (SRCB_LOG - WLOG);  // 256 windows/bin
static constexpr int NWAVE    = 16;              // waves per agg/wplace block

// ---------------- common ----------------

__global__ void node_init(const float4* __restrict__ x,
                          const float* __restrict__ W0n,
                          const float* __restrict__ W0s,
                          float* __restrict__ xw0,
                          float* __restrict__ s0,
                          int n_nodes) {
    int n = blockIdx.x * blockDim.x + threadIdx.x;
    if (n >= n_nodes) return;
    float4 a = x[2 * n];
    float4 b = x[2 * n + 1];
    float xn = a.x * W0n[0] + a.y * W0n[1] + a.z * W0n[2] + a.w * W0n[3] +
               b.x * W0n[4] + b.y * W0n[5] + b.z * W0n[6] + b.w * W0n[7];
    float xs = a.x * W0s[0] + a.y * W0s[1] + a.z * W0s[2] + a.w * W0s[3] +
               b.x * W0s[4] + b.y * W0s[5] + b.z * W0s[6] + b.w * W0s[7];
    xw0[n] = xn;
    s0[n] = xs;
}

__global__ void head(const float* __restrict__ hg,
                     const float* __restrict__ fc1_w,
                     const float* __restrict__ fc1_b,
                     const float* __restrict__ out_w,
                     const float* __restrict__ out_b,
                     float* __restrict__ out) {
    int gph = threadIdx.x;
    if (gph >= NGRAPHS) return;
    float hv = hg[gph];
    float o0 = out_b[0], o1 = out_b[1], o2 = out_b[2], o3 = out_b[3];
#pragma unroll
    for (int j = 0; j < 8; ++j) {
        float z = (hv * fc1_w[j] + fc1_b[j]) * 1000.0f;
        float sg = 1.0f / (1.0f + expf(-z));
        o0 += sg * out_w[j * 4 + 0];
        o1 += sg * out_w[j * 4 + 1];
        o2 += sg * out_w[j * 4 + 2];
        o3 += sg * out_w[j * 4 + 3];
    }
    o0 = fmaxf(o0, 0.0f); o1 = fmaxf(o1, 0.0f);
    o2 = fmaxf(o2, 0.0f); o3 = fmaxf(o3, 0.0f);
    float m = fmaxf(fmaxf(o0, o1), fmaxf(o2, o3));
    float s = expf(o0 - m) + expf(o1 - m) + expf(o2 - m) + expf(o3 - m);
    float l = logf(s);
    out[gph * 4 + 0] = o0 - m - l;
    out[gph * 4 + 1] = o1 - m - l;
    out[gph * 4 + 2] = o2 - m - l;
    out[gph * 4 + 3] = o3 - m - l;
}

__device__ __forceinline__ int bin1_of(int d, int s) {
    return ((d >> DSTB_LOG) << NSB_LOG) | ((unsigned)s >> SRCB_LOG);
}
__device__ __forceinline__ uint32_t rec_of(int d, int s) {
    return ((uint32_t)(d & (DSTB - 1)) << SRCB_LOG) | ((uint32_t)s & SRCMASK);
}

// ---------------- build ----------------

__global__ void count_chunks(const int* __restrict__ src,
                             const int* __restrict__ dst,
                             int n_edges, int nbins,
                             int* __restrict__ chunk_hist) {
    __shared__ int hist[MAXB];
    for (int i = threadIdx.x; i < MAXB; i += blockDim.x) hist[i] = 0;
    __syncthreads();
    const int nq = n_edges >> 2;
    const int per = (nq + NCHUNK - 1) / NCHUNK;
    const int b0 = blockIdx.x * per;
    const int b1 = min(b0 + per, nq);
    const bool last = (blockIdx.x == NCHUNK - 1);
    const int4* s4 = (const int4*)src;
    const int4* d4 = (const int4*)dst;
    for (int q = b0 + threadIdx.x; q < b1; q += blockDim.x) {
        int4 d = d4[q]; int4 s = s4[q];
        atomicAdd(&hist[bin1_of(d.x, s.x)], 1);
        atomicAdd(&hist[bin1_of(d.y, s.y)], 1);
        atomicAdd(&hist[bin1_of(d.z, s.z)], 1);
        atomicAdd(&hist[bin1_of(d.w, s.w)], 1);
    }
    if (last) {
        for (int e = (nq << 2) + threadIdx.x; e < n_edges; e += blockDim.x)
            atomicAdd(&hist[bin1_of(dst[e], src[e])], 1);
    }
    __syncthreads();
    for (int i = threadIdx.x; i < MAXB; i += blockDim.x)
        chunk_hist[blockIdx.x * MAXB + i] = hist[i];
}

__global__ void chunk_scan(const int* __restrict__ chunk_hist, int nbins,
                           int* __restrict__ offs, int* __restrict__ cursors) {
    __shared__ int lds[MAXB];
    const int b = threadIdx.x;
    int total = 0;
    if (b < nbins)
        for (int c = 0; c < NCHUNK; ++c) total += chunk_hist[c * MAXB + b];
    lds[b] = total;
    __syncthreads();
    for (int off = 1; off < MAXB; off <<= 1) {
        int v = (b >= off) ? lds[b - off] : 0;
        __syncthreads();
        lds[b] += v;
        __syncthreads();
    }
    int excl = lds[b] - total;
    offs[b] = excl;
    if (b == MAXB - 1) offs[MAXB] = lds[MAXB - 1];
    if (b < nbins) {
        int run = excl;
        for (int c = 0; c < NCHUNK; ++c) {
            cursors[c * MAXB + b] = run;
            run += chunk_hist[c * MAXB + b];
        }
    }
}

__global__ void place1(const int* __restrict__ src,
                       const int* __restrict__ dst,
                       int n_edges, int nbins,
                       const int* __restrict__ cursors,
                       uint32_t* __restrict__ sorted) {
    __shared__ int cur[MAXB];
    for (int i = threadIdx.x; i < MAXB; i += blockDim.x)
        cur[i] = cursors[blockIdx.x * MAXB + i];
    __syncthreads();
    const int nq = n_edges >> 2;
    const int per = (nq + NCHUNK - 1) / NCHUNK;
    const int b0 = blockIdx.x * per;
    const int b1 = min(b0 + per, nq);
    const bool last = (blockIdx.x == NCHUNK - 1);
    const int4* s4 = (const int4*)src;
    const int4* d4 = (const int4*)dst;
    for (int q = b0 + threadIdx.x; q < b1; q += blockDim.x) {
        int4 d = d4[q]; int4 s = s4[q];
        int p0 = atomicAdd(&cur[bin1_of(d.x, s.x)], 1);
        int p1 = atomicAdd(&cur[bin1_of(d.y, s.y)], 1);
        int p2 = atomicAdd(&cur[bin1_of(d.z, s.z)], 1);
        int p3 = atomicAdd(&cur[bin1_of(d.w, s.w)], 1);
        sorted[p0] = rec_of(d.x, s.x);
        sorted[p1] = rec_of(d.y, s.y);
        sorted[p2] = rec_of(d.z, s.z);
        sorted[p3] = rec_of(d.w, s.w);
    }
    if (last) {
        for (int e = (nq << 2) + threadIdx.x; e < n_edges; e += blockDim.x) {
            int pos = atomicAdd(&cur[bin1_of(dst[e], src[e])], 1);
            sorted[pos] = rec_of(dst[e], src[e]);
        }
    }
}

// Per-bin window sort into 256 windows of 1024 srcs. Per-wave histograms and
// cursors; 256 output runs -> 16KB active write lines per block (no thrash).
__global__ __launch_bounds__(1024) void wplace(const uint32_t* __restrict__ s1,
                                               const int* __restrict__ offs,
                                               uint32_t* __restrict__ s2,
                                               int* __restrict__ woffs) {
    __shared__ int whist[NWAVE][NWIN];   // 16KB
    __shared__ int wbase[NWAVE][NWIN];   // 16KB
    __shared__ int wtot[NWIN];
    __shared__ int wrun[NWIN];
    const int bin = blockIdx.x;
    const int tid = threadIdx.x;
    const int wv = tid >> 6;
    const int beg = offs[bin], end = offs[bin + 1];
    for (int i = tid; i < NWAVE * NWIN; i += 1024) ((int*)whist)[i] = 0;
    __syncthreads();
    // phase A: per-wave window histogram (uint4 reads)
    {
        int vbeg = min((beg + 3) & ~3, end);
        int vend = (vbeg < end) ? (end & ~3) : vbeg;
        for (int e = beg + tid; e < vbeg; e += 1024)
            atomicAdd(&whist[wv][(s1[e] >> WLOG) & (NWIN - 1)], 1);
        const uint4* s1q = (const uint4*)s1;
        for (int q = (vbeg >> 2) + tid; q < (vend >> 2); q += 1024) {
            uint4 r = s1q[q];
            atomicAdd(&whist[wv][(r.x >> WLOG) & (NWIN - 1)], 1);
            atomicAdd(&whist[wv][(r.y >> WLOG) & (NWIN - 1)], 1);
            atomicAdd(&whist[wv][(r.z >> WLOG) & (NWIN - 1)], 1);
            atomicAdd(&whist[wv][(r.w >> WLOG) & (NWIN - 1)], 1);
        }
        for (int e = max(vend, beg) + tid; e < end; e += 1024)
            atomicAdd(&whist[wv][(s1[e] >> WLOG) & (NWIN - 1)], 1);
    }
    __syncthreads();
    if (tid < NWIN) {
        int t = 0;
#pragma unroll
        for (int v = 0; v < NWAVE; ++v) t += whist[v][tid];
        wtot[tid] = t;
        wrun[tid] = t;
    }
    __syncthreads();
    for (int off = 1; off < NWIN; off <<= 1) {
        int v = (tid < NWIN && tid >= off) ? wrun[tid - off] : 0;
        __syncthreads();
        if (tid < NWIN) wrun[tid] += v;
        __syncthreads();
    }
    if (tid < NWIN) {
        int excl = wrun[tid] - wtot[tid];
        wrun[tid] = excl;
        woffs[bin * (NWIN + 1) + tid] = beg + excl;
    }
    if (tid == 0) woffs[bin * (NWIN + 1) + NWIN] = end;
    __syncthreads();
    if (tid < NWIN) {
        int run = wrun[tid];
#pragma unroll
        for (int v = 0; v < NWAVE; ++v) { wbase[v][tid] = run; run += whist[v][tid]; }
    }
    __syncthreads();
    // phase C: place with per-wave cursors (s1 reads L2/L3-hot)
    {
        int vbeg = min((beg + 3) & ~3, end);
        int vend = (vbeg < end) ? (end & ~3) : vbeg;
        for (int e = beg + tid; e < vbeg; e += 1024) {
            uint32_t r = s1[e];
            int p = atomicAdd(&wbase[wv][(r >> WLOG) & (NWIN - 1)], 1);
            s2[beg + p] = r;
        }
        const uint4* s1q = (const uint4*)s1;
        for (int q = (vbeg >> 2) + tid; q < (vend >> 2); q += 1024) {
            uint4 r = s1q[q];
            int p0 = atomicAdd(&wbase[wv][(r.x >> WLOG) & (NWIN - 1)], 1);
            int p1 = atomicAdd(&wbase[wv][(r.y >> WLOG) & (NWIN - 1)], 1);
            int p2 = atomicAdd(&wbase[wv][(r.z >> WLOG) & (NWIN - 1)], 1);
            int p3 = atomicAdd(&wbase[wv][(r.w >> WLOG) & (NWIN - 1)], 1);
            s2[beg + p0] = r.x;
            s2[beg + p1] = r.y;
            s2[beg + p2] = r.z;
            s2[beg + p3] = r.w;
        }
        for (int e = max(vend, beg) + tid; e < end; e += 1024) {
            uint32_t r = s1[e];
            int p = atomicAdd(&wbase[wv][(r >> WLOG) & (NWIN - 1)], 1);
            s2[beg + p] = r;
        }
    }
}

// ---------------- per-layer aggregation: wave-private LDS slabs ----------------

__global__ __launch_bounds__(1024) void wave_agg(const uint32_t* __restrict__ s2,
                                                 const int* __restrict__ woffs,
                                                 const float* __restrict__ gsrc,
                                                 float* __restrict__ partial) {
    __shared__ float acc[DSTB];            // 64 KB (shared by all waves)
    __shared__ float slab[NWAVE][1 << WLOG]; // 64 KB (4KB private per wave)
    const int bin = blockIdx.x;
    const int tid = threadIdx.x;
    const int wv = tid >> 6;
    const int lane = tid & 63;
    for (int i = tid; i < DSTB; i += 1024) acc[i] = 0.0f;
    __syncthreads();   // acc ready (the ONLY barrier before writeout)

    const float* sb = gsrc + ((size_t)(bin & ((1 << NSB_LOG) - 1)) << SRCB_LOG);
    const int* wo = woffs + bin * (NWIN + 1);
    const int w0 = wv * (NWIN / NWAVE);       // blocked window assignment
    const int w1 = w0 + (NWIN / NWAVE);
    float4* slq = (float4*)slab[wv];

    // prefetch first window into registers
    const float4* gw = (const float4*)(sb + ((size_t)w0 << WLOG));
    float4 n0 = gw[lane];
    float4 n1 = gw[64 + lane];
    float4 n2 = gw[128 + lane];
    float4 n3 = gw[192 + lane];

    for (int w = w0; w < w1; ++w) {
        // write staged window to this wave's slab
        slq[lane] = n0;
        slq[64 + lane] = n1;
        slq[128 + lane] = n2;
        slq[192 + lane] = n3;
        // issue next window's loads (latency hides under edge processing)
        if (w + 1 < w1) {
            const float4* gn = (const float4*)(sb + ((size_t)(w + 1) << WLOG));
            n0 = gn[lane];
            n1 = gn[64 + lane];
            n2 = gn[128 + lane];
            n3 = gn[192 + lane];
        }
        // process this window's edges: pure LDS per edge, wave-private order
        const int es = wo[w], ee = wo[w + 1];
        for (int e = es + lane; e < ee; e += 64) {
            uint32_t r = s2[e];
            atomicAdd(&acc[r >> SRCB_LOG], slab[wv][r & ((1 << WLOG) - 1)]);
        }
    }
    __syncthreads();
    float* o = partial + (size_t)bin * DSTB;
    for (int i = tid; i < DSTB; i += 1024) o[i] = acc[i];
}

// ---------------- reduce (4 partial rows per dst bucket) + node update ----------------

__global__ void reduce_l0(const float* __restrict__ partial,
                          const float* __restrict__ s0,
                          const float* __restrict__ b0,
                          float* __restrict__ h_out, int n_nodes) {
    const float bb = b0[0];
    const int stride = gridDim.x * blockDim.x;
    for (int n = blockIdx.x * blockDim.x + threadIdx.x; n < n_nodes; n += stride) {
        const float* p = partial + ((size_t)(n >> DSTB_LOG) << (NSB_LOG + DSTB_LOG)) + (n & (DSTB - 1));
        float v = p[0] + p[(size_t)1 << DSTB_LOG] + p[(size_t)2 << DSTB_LOG] + p[(size_t)3 << DSTB_LOG];
        h_out[n] = fmaxf(v + bb + s0[n], 0.0f);
    }
}

__global__ void reduce_lk(const float* __restrict__ partial,
                          const float* __restrict__ h_in,
                          const float* __restrict__ Wkn,
                          const float* __restrict__ bk,
                          const float* __restrict__ Wks,
                          int li, float* __restrict__ h_out, int n_nodes) {
    const float wn = Wkn[li], bb = bk[li], ws = Wks[li];
    const int stride = gridDim.x * blockDim.x;
    for (int n = blockIdx.x * blockDim.x + threadIdx.x; n < n_nodes; n += stride) {
        const float* p = partial + ((size_t)(n >> DSTB_LOG) << (NSB_LOG + DSTB_LOG)) + (n & (DSTB - 1));
        float v = p[0] + p[(size_t)1 << DSTB_LOG] + p[(size_t)2 << DSTB_LOG] + p[(size_t)3 << DSTB_LOG];
        h_out[n] = fmaxf(wn * v + bb + ws * h_in[n], 0.0f);
    }
}

__global__ void reduce_last(const float* __restrict__ partial,
                            const float* __restrict__ h_in,
                            const int* __restrict__ graph_ids,
                            const float* __restrict__ Wkn,
                            const float* __restrict__ bk,
                            const float* __restrict__ Wks,
                            int li, float* __restrict__ hg, int n_nodes) {
    const float wn = Wkn[li], bb = bk[li], ws = Wks[li];
    const int stride = gridDim.x * blockDim.x;
    const int nloop = (n_nodes + stride - 1) / stride * stride;  // uniform trips
    for (int n = blockIdx.x * blockDim.x + threadIdx.x; n < nloop; n += stride) {
        float val = 0.0f;
        int g = -1;
        if (n < n_nodes) {
            const float* p = partial + ((size_t)(n >> DSTB_LOG) << (NSB_LOG + DSTB_LOG)) + (n & (DSTB - 1));
            float v = p[0] + p[(size_t)1 << DSTB_LOG] + p[(size_t)2 << DSTB_LOG] + p[(size_t)3 << DSTB_LOG];
            val = fmaxf(wn * v + bb + ws * h_in[n], 0.0f);
            g = graph_ids[n];
        }
        int g0 = __shfl(g, 0);
        unsigned long long same = __ballot(g == g0);
        if (same == ~0ULL) {
            for (int o = 32; o > 0; o >>= 1) val += __shfl_down(val, o);
            if ((threadIdx.x & 63) == 0 && g >= 0) atomicAdd(&hg[g], val);
        } else if (g >= 0) {
            atomicAdd(&hg[g], val);
        }
    }
}

// ---------------- fallback: global atomics ----------------

__global__ void edge_scatter(const int4* __restrict__ src4,
                             const int4* __restrict__ dst4,
                             const float* __restrict__ val,
                             float* __restrict__ agg, int nquads) {
    int t = blockIdx.x * blockDim.x + threadIdx.x;
    if (t >= nquads) return;
    int4 s = src4[t]; int4 d = dst4[t];
    atomicAdd(&agg[d.x], val[s.x]);
    atomicAdd(&agg[d.y], val[s.y]);
    atomicAdd(&agg[d.z], val[s.z]);
    atomicAdd(&agg[d.w], val[s.w]);
}

__global__ void node_l0(float* __restrict__ agg, const float* __restrict__ s0,
                        const float* __restrict__ b0, float* __restrict__ h, int n_nodes) {
    int n = blockIdx.x * blockDim.x + threadIdx.x;
    if (n >= n_nodes) return;
    h[n] = fmaxf(agg[n] + b0[0] + s0[n], 0.0f);
    agg[n] = 0.0f;
}

__global__ void node_lk(float* __restrict__ agg, float* __restrict__ h,
                        const float* __restrict__ Wkn, const float* __restrict__ bk,
                        const float* __restrict__ Wks, int li, int n_nodes) {
    int n = blockIdx.x * blockDim.x + threadIdx.x;
    if (n >= n_nodes) return;
    float v = Wkn[li] * agg[n] + bk[li] + Wks[li] * h[n];
    h[n] = fmaxf(v, 0.0f);
    agg[n] = 0.0f;
}

__global__ void node_l3_readout(const float* __restrict__ agg, const float* __restrict__ h,
                                const int* __restrict__ graph_ids,
                                const float* __restrict__ Wkn, const float* __restrict__ bk,
                                const float* __restrict__ Wks, float* __restrict__ hg,
                                int n_nodes) {
    int n = blockIdx.x * blockDim.x + threadIdx.x;
    float val = 0.0f;
    int g = -1;
    if (n < n_nodes) {
        val = fmaxf(Wkn[2] * agg[n] + bk[2] + Wks[2] * h[n], 0.0f);
        g = graph_ids[n];
    }
    int g0 = __shfl(g, 0);
    unsigned long long same = __ballot(g == g0);
    if (same == ~0ULL) {
        for (int o = 32; o > 0; o >>= 1) val += __shfl_down(val, o);
        if ((threadIdx.x & 63) == 0 && g >= 0) atomicAdd(&hg[g], val);
    } else if (g >= 0) {
        atomicAdd(&hg[g], val);
    }
}

// ---------------- launch ----------------

extern "C" void kernel_launch(void* const* d_in, const int* in_sizes, int n_in,
                              void* d_out, int out_size, void* d_ws, size_t ws_size,
                              hipStream_t stream) {
    const float* x        = (const float*)d_in[0];
    const int*   src      = (const int*)d_in[1];
    const int*   dst      = (const int*)d_in[2];
    const int*   graphids = (const int*)d_in[3];
    const float* W0n   = (const float*)d_in[5];
    const float* b0    = (const float*)d_in[6];
    const float* W0s   = (const float*)d_in[7];
    const float* Wkn   = (const float*)d_in[8];
    const float* bk    = (const float*)d_in[9];
    const float* Wks   = (const float*)d_in[10];
    const float* fc1_w = (const float*)d_in[11];
    const float* fc1_b = (const float*)d_in[12];
    const float* out_w = (const float*)d_in[13];
    const float* out_b = (const float*)d_in[14];
    float* out = (float*)d_out;

    const int n_nodes = in_sizes[0] / 8;
    const int n_edges = in_sizes[1];
    const int nbd     = (n_nodes + DSTB - 1) >> DSTB_LOG;          // dst buckets (62)
    const int nbins   = nbd << NSB_LOG;                            // x 4 src blocks (248)
    const int node_blocks = (n_nodes + TB - 1) / TB;

    const size_t E4    = (size_t)n_edges * 4;
    const size_t NBP   = (size_t)(1 << 20) * sizeof(float);        // padded node array (4MB)
    const size_t part_bytes = (size_t)nbins * DSTB * sizeof(float);
    const size_t ov_need    = 4 * NBP + part_bytes;
    const size_t ov_bytes   = (ov_need > E4) ? ov_need : E4;
    const size_t tail_bytes = (MAXB + 1) * sizeof(int) +
                              (size_t)MAXB * (NWIN + 1) * sizeof(int) +
                              NGRAPHS * sizeof(float) + 256;
    const size_t need_full  = E4 + ov_bytes + tail_bytes;
    const size_t overlay_bytes = (size_t)2 * NCHUNK * MAXB * sizeof(int);

    const bool shape_ok = (nbins <= MAXB) && (n_nodes <= (1 << 20)) &&
                          (n_edges >= 4) && (E4 >= overlay_bytes);

    if (shape_ok && ws_size >= need_full) {
        // ---- FULL path ----
        char* ws = (char*)d_ws;
        uint32_t* s2 = (uint32_t*)ws;                      ws += E4;
        char* ov = ws;                                     ws += ov_bytes;
        uint32_t* s1 = (uint32_t*)ov;                      // build-time alias
        float* xw0 = (float*)(ov);
        float* s0  = (float*)(ov + NBP);
        float* h_a = (float*)(ov + 2 * NBP);
        float* h_b = (float*)(ov + 3 * NBP);
        float* partial = (float*)(ov + 4 * NBP);
        int* offs   = (int*)ws;                            ws += (MAXB + 1) * sizeof(int);
        int* woffs  = (int*)ws;                            ws += (size_t)MAXB * (NWIN + 1) * sizeof(int);
        float* hg   = (float*)ws;
        int* chunk_hist = (int*)s2;                        // overlay in s2 head
        int* cursors    = chunk_hist + NCHUNK * MAXB;

        hipMemsetAsync(hg, 0, NGRAPHS * sizeof(float), stream);

        count_chunks<<<NCHUNK, TB_P, 0, stream>>>(src, dst, n_edges, nbins, chunk_hist);
        chunk_scan<<<1, MAXB, 0, stream>>>(chunk_hist, nbins, offs, cursors);
        place1<<<NCHUNK, TB_P, 0, stream>>>(src, dst, n_edges, nbins, cursors, s1);
        wplace<<<nbins, 1024, 0, stream>>>(s1, offs, s2, woffs);
        // s1 dead: overlay node arrays + partials
        node_init<<<node_blocks, TB, 0, stream>>>((const float4*)x, W0n, W0s, xw0, s0, n_nodes);

        wave_agg<<<nbins, 1024, 0, stream>>>(s2, woffs, xw0, partial);
        reduce_l0<<<1024, 256, 0, stream>>>(partial, s0, b0, h_a, n_nodes);

        wave_agg<<<nbins, 1024, 0, stream>>>(s2, woffs, h_a, partial);
        reduce_lk<<<1024, 256, 0, stream>>>(partial, h_a, Wkn, bk, Wks, 0, h_b, n_nodes);

        wave_agg<<<nbins, 1024, 0, stream>>>(s2, woffs, h_b, partial);
        reduce_lk<<<1024, 256, 0, stream>>>(partial, h_b, Wkn, bk, Wks, 1, h_a, n_nodes);

        wave_agg<<<nbins, 1024, 0, stream>>>(s2, woffs, h_a, partial);
        reduce_last<<<1024, 256, 0, stream>>>(partial, h_a, graphids, Wkn, bk, Wks, 2, hg, n_nodes);

        head<<<1, TB, 0, stream>>>(hg, fc1_w, fc1_b, out_w, out_b, out);
    } else {
        // ---- fallback: global atomics ----
        const size_t NB = (size_t)n_nodes * sizeof(float);
        char* ws   = (char*)d_ws;
        float* agg = (float*)(ws);
        float* h   = (float*)(ws + NB);
        float* xw0 = (float*)(ws + 2 * NB);
        float* s0  = (float*)(ws + 3 * NB);
        float* hg  = (float*)(ws + 4 * NB);
        const int nquads = n_edges >> 2;
        const int edge_blocks = (nquads + TB - 1) / TB;

        hipMemsetAsync(agg, 0, NB, stream);
        hipMemsetAsync(hg, 0, NGRAPHS * sizeof(float), stream);

        node_init<<<node_blocks, TB, 0, stream>>>((const float4*)x, W0n, W0s, xw0, s0, n_nodes);
        edge_scatter<<<edge_blocks, TB, 0, stream>>>((const int4*)src, (const int4*)dst, xw0, agg, nquads);
        node_l0<<<node_blocks, TB, 0, stream>>>(agg, s0, b0, h, n_nodes);
        for (int li = 0; li < 2; ++li) {
            edge_scatter<<<edge_blocks, TB, 0, stream>>>((const int4*)src, (const int4*)dst, h, agg, nquads);
            node_lk<<<node_blocks, TB, 0, stream>>>(agg, h, Wkn, bk, Wks, li, n_nodes);
        }
        edge_scatter<<<edge_blocks, TB, 0, stream>>>((const int4*)src, (const int4*)dst, h, agg, nquads);
        node_l3_readout<<<node_blocks, TB, 0, stream>>>(agg, h, graphids, Wkn, bk, Wks, hg, n_nodes);
        head<<<1, TB, 0, stream>>>(hg, fc1_w, fc1_b, out_w, out_b, out);
    }
}

// Round 12
// 523.192 us; speedup vs baseline: 1.5628x; 1.5628x over previous
//
#include <hip/hip_runtime.h>
#include <stdint.h>

// GCN, DIM=1. Final assembly of measured-best pieces:
//  - count_chunks (dst-only read) -> chunk_scan -> place1 (cursor-precomputed
//    single-pass scatter into 4096-node dst buckets; rec = dstloc12<<20|src)
//  - 4 fused layer kernels (R3 structure): 16KB LDS acc per bucket, gather
//    h[src] directly, fused bias/ReLU (+sorted-graph readout on last layer).
// Window sorting / partial-sum splits / LDS staging all measured neutral or
// negative (R5-R11); aggregation is pinned at ~96us/pass regardless.

static constexpr int NGRAPHS   = 256;
static constexpr int TB        = 256;
static constexpr int TB_P      = 512;   // place/count block
static constexpr int NCHUNK    = 256;   // edge chunks (count & place)
static constexpr int TB_A      = 1024;  // layer block
static constexpr int BNODE_LOG = 12;
static constexpr int BNODE     = 1 << BNODE_LOG;  // 4096 dst nodes per bucket
static constexpr int MAXBUCK   = 256;
static constexpr int LOCAL_SHIFT = 20;            // dstloc in bits 20..31

// ---------------- common ----------------

__global__ void node_init(const float4* __restrict__ x,
                          const float* __restrict__ W0n,
                          const float* __restrict__ W0s,
                          float* __restrict__ xw0,
                          float* __restrict__ s0,
                          int n_nodes) {
    int n = blockIdx.x * blockDim.x + threadIdx.x;
    if (n >= n_nodes) return;
    float4 a = x[2 * n];
    float4 b = x[2 * n + 1];
    float xn = a.x * W0n[0] + a.y * W0n[1] + a.z * W0n[2] + a.w * W0n[3] +
               b.x * W0n[4] + b.y * W0n[5] + b.z * W0n[6] + b.w * W0n[7];
    float xs = a.x * W0s[0] + a.y * W0s[1] + a.z * W0s[2] + a.w * W0s[3] +
               b.x * W0s[4] + b.y * W0s[5] + b.z * W0s[6] + b.w * W0s[7];
    xw0[n] = xn;
    s0[n] = xs;
}

__global__ void head(const float* __restrict__ hg,
                     const float* __restrict__ fc1_w,
                     const float* __restrict__ fc1_b,
                     const float* __restrict__ out_w,
                     const float* __restrict__ out_b,
                     float* __restrict__ out) {
    int gph = threadIdx.x;
    if (gph >= NGRAPHS) return;
    float hv = hg[gph];
    float o0 = out_b[0], o1 = out_b[1], o2 = out_b[2], o3 = out_b[3];
#pragma unroll
    for (int j = 0; j < 8; ++j) {
        float z = (hv * fc1_w[j] + fc1_b[j]) * 1000.0f;
        float sg = 1.0f / (1.0f + expf(-z));
        o0 += sg * out_w[j * 4 + 0];
        o1 += sg * out_w[j * 4 + 1];
        o2 += sg * out_w[j * 4 + 2];
        o3 += sg * out_w[j * 4 + 3];
    }
    o0 = fmaxf(o0, 0.0f); o1 = fmaxf(o1, 0.0f);
    o2 = fmaxf(o2, 0.0f); o3 = fmaxf(o3, 0.0f);
    float m = fmaxf(fmaxf(o0, o1), fmaxf(o2, o3));
    float s = expf(o0 - m) + expf(o1 - m) + expf(o2 - m) + expf(o3 - m);
    float l = logf(s);
    out[gph * 4 + 0] = o0 - m - l;
    out[gph * 4 + 1] = o1 - m - l;
    out[gph * 4 + 2] = o2 - m - l;
    out[gph * 4 + 3] = o3 - m - l;
}

// ---------------- build ----------------

// Per-chunk bucket histograms (dst-only read). Chunk decomposition MUST
// match place1's.
__global__ void count_chunks(const int* __restrict__ dst,
                             int n_edges,
                             int* __restrict__ chunk_hist) {
    __shared__ int hist[MAXBUCK];
    for (int i = threadIdx.x; i < MAXBUCK; i += blockDim.x) hist[i] = 0;
    __syncthreads();
    const int nq = n_edges >> 2;
    const int per = (nq + NCHUNK - 1) / NCHUNK;
    const int b0 = blockIdx.x * per;
    const int b1 = min(b0 + per, nq);
    const bool last = (blockIdx.x == NCHUNK - 1);
    const int4* d4 = (const int4*)dst;
    for (int q = b0 + threadIdx.x; q < b1; q += blockDim.x) {
        int4 d = d4[q];
        atomicAdd(&hist[d.x >> BNODE_LOG], 1);
        atomicAdd(&hist[d.y >> BNODE_LOG], 1);
        atomicAdd(&hist[d.z >> BNODE_LOG], 1);
        atomicAdd(&hist[d.w >> BNODE_LOG], 1);
    }
    if (last) {
        for (int e = (nq << 2) + threadIdx.x; e < n_edges; e += blockDim.x)
            atomicAdd(&hist[dst[e] >> BNODE_LOG], 1);
    }
    __syncthreads();
    for (int i = threadIdx.x; i < MAXBUCK; i += blockDim.x)
        chunk_hist[blockIdx.x * MAXBUCK + i] = hist[i];
}

// One block: bucket offsets + exact per-(chunk,bucket) cursors.
__global__ void chunk_scan(const int* __restrict__ chunk_hist, int nbuck,
                           int* __restrict__ offs, int* __restrict__ cursors) {
    __shared__ int lds[MAXBUCK];
    const int b = threadIdx.x;
    int total = 0;
    if (b < nbuck)
        for (int c = 0; c < NCHUNK; ++c) total += chunk_hist[c * MAXBUCK + b];
    lds[b] = total;
    __syncthreads();
    for (int off = 1; off < MAXBUCK; off <<= 1) {
        int v = (b >= off) ? lds[b - off] : 0;
        __syncthreads();
        lds[b] += v;
        __syncthreads();
    }
    int excl = lds[b] - total;
    offs[b] = excl;
    if (b == MAXBUCK - 1) offs[MAXBUCK] = lds[MAXBUCK - 1];
    if (b < nbuck) {
        int run = excl;
        for (int c = 0; c < NCHUNK; ++c) {
            cursors[c * MAXBUCK + b] = run;
            run += chunk_hist[c * MAXBUCK + b];
        }
    }
}

// Single-pass bucket scatter with precomputed cursors. 245 active write
// regions/block (16KB of lines) -> no writeback thrash.
__global__ void place1(const int* __restrict__ src,
                       const int* __restrict__ dst,
                       int n_edges,
                       const int* __restrict__ cursors,
                       uint32_t* __restrict__ sorted) {
    __shared__ int cur[MAXBUCK];
    for (int i = threadIdx.x; i < MAXBUCK; i += blockDim.x)
        cur[i] = cursors[blockIdx.x * MAXBUCK + i];
    __syncthreads();
    const int nq = n_edges >> 2;
    const int per = (nq + NCHUNK - 1) / NCHUNK;
    const int b0 = blockIdx.x * per;
    const int b1 = min(b0 + per, nq);
    const bool last = (blockIdx.x == NCHUNK - 1);
    const int4* s4 = (const int4*)src;
    const int4* d4 = (const int4*)dst;
    for (int q = b0 + threadIdx.x; q < b1; q += blockDim.x) {
        int4 d = d4[q]; int4 s = s4[q];
        int p0 = atomicAdd(&cur[d.x >> BNODE_LOG], 1);
        int p1 = atomicAdd(&cur[d.y >> BNODE_LOG], 1);
        int p2 = atomicAdd(&cur[d.z >> BNODE_LOG], 1);
        int p3 = atomicAdd(&cur[d.w >> BNODE_LOG], 1);
        sorted[p0] = ((uint32_t)(d.x & (BNODE - 1)) << LOCAL_SHIFT) | (uint32_t)s.x;
        sorted[p1] = ((uint32_t)(d.y & (BNODE - 1)) << LOCAL_SHIFT) | (uint32_t)s.y;
        sorted[p2] = ((uint32_t)(d.z & (BNODE - 1)) << LOCAL_SHIFT) | (uint32_t)s.z;
        sorted[p3] = ((uint32_t)(d.w & (BNODE - 1)) << LOCAL_SHIFT) | (uint32_t)s.w;
    }
    if (last) {
        for (int e = (nq << 2) + threadIdx.x; e < n_edges; e += blockDim.x) {
            int d = dst[e];
            int pos = atomicAdd(&cur[d >> BNODE_LOG], 1);
            sorted[pos] = ((uint32_t)(d & (BNODE - 1)) << LOCAL_SHIFT) | (uint32_t)src[e];
        }
    }
}

// ---------------- fused layer kernels ----------------

__device__ __forceinline__ void bucket_accumulate(const uint32_t* __restrict__ sorted,
                                                  int beg, int end,
                                                  const float* __restrict__ gsrc,
                                                  float* acc) {
    const int tid = threadIdx.x;
    for (int i = tid; i < BNODE; i += TB_A) acc[i] = 0.0f;
    __syncthreads();
    int vbeg = min((beg + 3) & ~3, end);
    int vend = (vbeg < end) ? (end & ~3) : vbeg;
    for (int e = beg + tid; e < vbeg; e += TB_A) {
        uint32_t r = sorted[e];
        atomicAdd(&acc[r >> LOCAL_SHIFT], gsrc[r & 0xFFFFFu]);
    }
    const uint4* sq = (const uint4*)sorted;
    for (int q = (vbeg >> 2) + tid; q < (vend >> 2); q += TB_A) {
        uint4 r = sq[q];
        float v0 = gsrc[r.x & 0xFFFFFu];
        float v1 = gsrc[r.y & 0xFFFFFu];
        float v2 = gsrc[r.z & 0xFFFFFu];
        float v3 = gsrc[r.w & 0xFFFFFu];
        atomicAdd(&acc[r.x >> LOCAL_SHIFT], v0);
        atomicAdd(&acc[r.y >> LOCAL_SHIFT], v1);
        atomicAdd(&acc[r.z >> LOCAL_SHIFT], v2);
        atomicAdd(&acc[r.w >> LOCAL_SHIFT], v3);
    }
    for (int e = max(vend, beg) + tid; e < end; e += TB_A) {
        uint32_t r = sorted[e];
        atomicAdd(&acc[r >> LOCAL_SHIFT], gsrc[r & 0xFFFFFu]);
    }
    __syncthreads();
}

__global__ __launch_bounds__(TB_A) void layer0_agg(const uint32_t* __restrict__ sorted,
                                                   const int* __restrict__ offs,
                                                   const float* __restrict__ xw0,
                                                   const float* __restrict__ s0,
                                                   const float* __restrict__ b0,
                                                   float* __restrict__ h_out,
                                                   int n_nodes) {
    __shared__ float acc[BNODE];
    bucket_accumulate(sorted, offs[blockIdx.x], offs[blockIdx.x + 1], xw0, acc);
    int base = blockIdx.x << BNODE_LOG;
    int nloc = min(BNODE, n_nodes - base);
    float bb = b0[0];
    for (int i = threadIdx.x; i < nloc; i += TB_A) {
        int n = base + i;
        h_out[n] = fmaxf(acc[i] + bb + s0[n], 0.0f);
    }
}

__global__ __launch_bounds__(TB_A) void layerk_agg(const uint32_t* __restrict__ sorted,
                                                   const int* __restrict__ offs,
                                                   const float* __restrict__ h_in,
                                                   const float* __restrict__ Wkn,
                                                   const float* __restrict__ bk,
                                                   const float* __restrict__ Wks,
                                                   int li,
                                                   float* __restrict__ h_out,
                                                   int n_nodes) {
    __shared__ float acc[BNODE];
    bucket_accumulate(sorted, offs[blockIdx.x], offs[blockIdx.x + 1], h_in, acc);
    int base = blockIdx.x << BNODE_LOG;
    int nloc = min(BNODE, n_nodes - base);
    float wn = Wkn[li], bb = bk[li], ws = Wks[li];
    for (int i = threadIdx.x; i < nloc; i += TB_A) {
        int n = base + i;
        h_out[n] = fmaxf(wn * acc[i] + bb + ws * h_in[n], 0.0f);
    }
}

__global__ __launch_bounds__(TB_A) void layer_last_readout(const uint32_t* __restrict__ sorted,
                                                           const int* __restrict__ offs,
                                                           const float* __restrict__ h_in,
                                                           const int* __restrict__ graph_ids,
                                                           const float* __restrict__ Wkn,
                                                           const float* __restrict__ bk,
                                                           const float* __restrict__ Wks,
                                                           int li,
                                                           float* __restrict__ hg,
                                                           int n_nodes) {
    __shared__ float acc[BNODE];
    bucket_accumulate(sorted, offs[blockIdx.x], offs[blockIdx.x + 1], h_in, acc);
    int base = blockIdx.x << BNODE_LOG;
    int nloc = min(BNODE, n_nodes - base);
    float wn = Wkn[li], bb = bk[li], ws = Wks[li];
    for (int i = threadIdx.x; i < BNODE; i += TB_A) {   // uniform bound for wave ops
        float val = 0.0f;
        int g = -1;
        if (i < nloc) {
            int n = base + i;
            val = fmaxf(wn * acc[i] + bb + ws * h_in[n], 0.0f);
            g = graph_ids[n];
        }
        int g0 = __shfl(g, 0);
        unsigned long long same = __ballot(g == g0);
        if (same == ~0ULL) {
            for (int o = 32; o > 0; o >>= 1) val += __shfl_down(val, o);
            if ((threadIdx.x & 63) == 0 && g >= 0) atomicAdd(&hg[g], val);
        } else if (g >= 0) {
            atomicAdd(&hg[g], val);
        }
    }
}

// ---------------- fallback: global atomics ----------------

__global__ void edge_scatter(const int4* __restrict__ src4,
                             const int4* __restrict__ dst4,
                             const float* __restrict__ val,
                             float* __restrict__ agg, int nquads) {
    int t = blockIdx.x * blockDim.x + threadIdx.x;
    if (t >= nquads) return;
    int4 s = src4[t]; int4 d = dst4[t];
    atomicAdd(&agg[d.x], val[s.x]);
    atomicAdd(&agg[d.y], val[s.y]);
    atomicAdd(&agg[d.z], val[s.z]);
    atomicAdd(&agg[d.w], val[s.w]);
}

__global__ void node_l0(float* __restrict__ agg, const float* __restrict__ s0,
                        const float* __restrict__ b0, float* __restrict__ h, int n_nodes) {
    int n = blockIdx.x * blockDim.x + threadIdx.x;
    if (n >= n_nodes) return;
    h[n] = fmaxf(agg[n] + b0[0] + s0[n], 0.0f);
    agg[n] = 0.0f;
}

__global__ void node_lk(float* __restrict__ agg, float* __restrict__ h,
                        const float* __restrict__ Wkn, const float* __restrict__ bk,
                        const float* __restrict__ Wks, int li, int n_nodes) {
    int n = blockIdx.x * blockDim.x + threadIdx.x;
    if (n >= n_nodes) return;
    float v = Wkn[li] * agg[n] + bk[li] + Wks[li] * h[n];
    h[n] = fmaxf(v, 0.0f);
    agg[n] = 0.0f;
}

__global__ void node_l3_readout(const float* __restrict__ agg, const float* __restrict__ h,
                                const int* __restrict__ graph_ids,
                                const float* __restrict__ Wkn, const float* __restrict__ bk,
                                const float* __restrict__ Wks, float* __restrict__ hg,
                                int n_nodes) {
    int n = blockIdx.x * blockDim.x + threadIdx.x;
    float val = 0.0f;
    int g = -1;
    if (n < n_nodes) {
        val = fmaxf(Wkn[2] * agg[n] + bk[2] + Wks[2] * h[n], 0.0f);
        g = graph_ids[n];
    }
    int g0 = __shfl(g, 0);
    unsigned long long same = __ballot(g == g0);
    if (same == ~0ULL) {
        for (int o = 32; o > 0; o >>= 1) val += __shfl_down(val, o);
        if ((threadIdx.x & 63) == 0 && g >= 0) atomicAdd(&hg[g], val);
    } else if (g >= 0) {
        atomicAdd(&hg[g], val);
    }
}

// ---------------- launch ----------------

extern "C" void kernel_launch(void* const* d_in, const int* in_sizes, int n_in,
                              void* d_out, int out_size, void* d_ws, size_t ws_size,
                              hipStream_t stream) {
    const float* x        = (const float*)d_in[0];
    const int*   src      = (const int*)d_in[1];
    const int*   dst      = (const int*)d_in[2];
    const int*   graphids = (const int*)d_in[3];
    const float* W0n   = (const float*)d_in[5];
    const float* b0    = (const float*)d_in[6];
    const float* W0s   = (const float*)d_in[7];
    const float* Wkn   = (const float*)d_in[8];
    const float* bk    = (const float*)d_in[9];
    const float* Wks   = (const float*)d_in[10];
    const float* fc1_w = (const float*)d_in[11];
    const float* fc1_b = (const float*)d_in[12];
    const float* out_w = (const float*)d_in[13];
    const float* out_b = (const float*)d_in[14];
    float* out = (float*)d_out;

    const int n_nodes = in_sizes[0] / 8;
    const int n_edges = in_sizes[1];
    const int nbuck   = (n_nodes + BNODE - 1) >> BNODE_LOG;   // 245
    const int node_blocks = (n_nodes + TB - 1) / TB;

    const size_t E4   = (size_t)n_edges * 4;
    const size_t NBP  = (size_t)(1 << 20) * sizeof(float);    // 4MB per node array
    const size_t hist_bytes = (size_t)2 * NCHUNK * MAXBUCK * sizeof(int);  // 512KB
    const size_t ov_bytes = 4 * NBP;                          // xw0,s0,h_a,h_b
    const size_t tail_bytes = (MAXBUCK + 1) * sizeof(int) + NGRAPHS * sizeof(float) + 256;
    const size_t need_full = E4 + ov_bytes + tail_bytes;

    const bool shape_ok = (nbuck <= MAXBUCK) && (n_nodes <= (1 << 20)) &&
                          (n_edges >= 4) && (ov_bytes >= hist_bytes);

    if (shape_ok && ws_size >= need_full) {
        // ---- FULL path ----
        char* ws = (char*)d_ws;
        uint32_t* sorted = (uint32_t*)ws;                  ws += E4;
        char* ov = ws;                                     ws += ov_bytes;
        float* xw0 = (float*)(ov);
        float* s0  = (float*)(ov + NBP);
        float* h_a = (float*)(ov + 2 * NBP);
        float* h_b = (float*)(ov + 3 * NBP);
        int* offs  = (int*)ws;                             ws += (MAXBUCK + 1) * sizeof(int);
        float* hg  = (float*)ws;
        // chunk_hist + cursors overlay node arrays (dead until node_init)
        int* chunk_hist = (int*)ov;
        int* cursors    = chunk_hist + NCHUNK * MAXBUCK;

        hipMemsetAsync(hg, 0, NGRAPHS * sizeof(float), stream);

        count_chunks<<<NCHUNK, TB_P, 0, stream>>>(dst, n_edges, chunk_hist);
        chunk_scan<<<1, MAXBUCK, 0, stream>>>(chunk_hist, nbuck, offs, cursors);
        place1<<<NCHUNK, TB_P, 0, stream>>>(src, dst, n_edges, cursors, sorted);
        // cursors dead: overlay node arrays
        node_init<<<node_blocks, TB, 0, stream>>>((const float4*)x, W0n, W0s, xw0, s0, n_nodes);

        layer0_agg<<<nbuck, TB_A, 0, stream>>>(sorted, offs, xw0, s0, b0, h_a, n_nodes);
        layerk_agg<<<nbuck, TB_A, 0, stream>>>(sorted, offs, h_a, Wkn, bk, Wks, 0, h_b, n_nodes);
        layerk_agg<<<nbuck, TB_A, 0, stream>>>(sorted, offs, h_b, Wkn, bk, Wks, 1, h_a, n_nodes);
        layer_last_readout<<<nbuck, TB_A, 0, stream>>>(sorted, offs, h_a, graphids, Wkn, bk, Wks, 2, hg, n_nodes);

        head<<<1, TB, 0, stream>>>(hg, fc1_w, fc1_b, out_w, out_b, out);
    } else {
        // ---- fallback: global atomics ----
        const size_t NB = (size_t)n_nodes * sizeof(float);
        char* ws   = (char*)d_ws;
        float* agg = (float*)(ws);
        float* h   = (float*)(ws + NB);
        float* xw0 = (float*)(ws + 2 * NB);
        float* s0  = (float*)(ws + 3 * NB);
        float* hg  = (float*)(ws + 4 * NB);
        const int nquads = n_edges >> 2;
        const int edge_blocks = (nquads + TB - 1) / TB;

        hipMemsetAsync(agg, 0, NB, stream);
        hipMemsetAsync(hg, 0, NGRAPHS * sizeof(float), stream);

        node_init<<<node_blocks, TB, 0, stream>>>((const float4*)x, W0n, W0s, xw0, s0, n_nodes);
        edge_scatter<<<edge_blocks, TB, 0, stream>>>((const int4*)src, (const int4*)dst, xw0, agg, nquads);
        node_l0<<<node_blocks, TB, 0, stream>>>(agg, s0, b0, h, n_nodes);
        for (int li = 0; li < 2; ++li) {
            edge_scatter<<<edge_blocks, TB, 0, stream>>>((const int4*)src, (const int4*)dst, h, agg, nquads);
            node_lk<<<node_blocks, TB, 0, stream>>>(agg, h, Wkn, bk, Wks, li, n_nodes);
        }
        edge_scatter<<<edge_blocks, TB, 0, stream>>>((const int4*)src, (const int4*)dst, h, agg, nquads);
        node_l3_readout<<<node_blocks, TB, 0, stream>>>(agg, h, graphids, Wkn, bk, Wks, hg, n_nodes);
        head<<<1, TB, 0, stream>>>(hg, fc1_w, fc1_b, out_w, out_b, out);
    }
}